// Round 11
// baseline (210.310 us; speedup 1.0000x reference)
//
#include <hip/hip_runtime.h>
#include <hip/hip_bf16.h>
#include <math.h>

// Problem constants
#define BB 32
#define TT 4096
#define CC 64
#define DD 512
#define NW 31          // number of windows
#define WIN 256
#define HOP 128
#define NROWS (BB * NW)   // 992

typedef float f32x4 __attribute__((ext_vector_type(4)));

// ---------------------------------------------------------------------------
// Kernel 1: band power via folded Goertzel. (unchanged from round 4)
// ---------------------------------------------------------------------------
__global__ __launch_bounds__(512) void k_bandpower(const float* __restrict__ x,
                                                   float* __restrict__ feat) {
    __shared__ float lds[16384];         // 64 KB
    float* u = lds;                      // [128][64]
    float* v = lds + 8192;               // [128][64]

    const int tid = threadIdx.x;
    const int c   = tid & 63;
    const int g   = tid >> 6;            // wave id 0..7
    const int blk = blockIdx.x;          // 0..991
    const int b   = blk / NW;
    const int n   = blk % NW;

    // staged fold: read both halves once, write u,v (coalesced f32x4)
    const size_t winBase = ((size_t)b * TT + (size_t)n * HOP) * CC;
    const f32x4* h0 = (const f32x4*)(x + winBase);              // t = 0..127
    const f32x4* h1 = (const f32x4*)(x + winBase + 128 * CC);   // t = 128..255
    f32x4* u4 = (f32x4*)u;
    f32x4* v4 = (f32x4*)v;
    for (int i = tid; i < 2048; i += 512) {
        const f32x4 a  = h0[i];
        const f32x4 bb = h1[i];
        u4[i] = a + bb;
        v4[i] = a - bb;
    }
    __syncthreads();

    // 7 Goertzel chains per thread, 128 steps, on u (even f) or v (odd f)
    float coef[7], s1[7], s2[7];
#pragma unroll
    for (int j = 0; j < 7; ++j) {
        const int f = 1 + g + 8 * j;
        coef[j] = 2.0f * cospif((float)f * (1.0f / 128.0f)); // 2cos(2pi f/256)
        s1[j] = 0.0f;
        s2[j] = 0.0f;
    }
    // parity(f) = parity(1+g): g odd -> f even -> u; g even -> f odd -> v
    const float* src = ((g & 1) ? u : v) + c;

#pragma unroll 4
    for (int tt = 0; tt < 128; ++tt) {
        const float xv = src[tt * 64];
#pragma unroll
        for (int j = 0; j < 7; ++j) {
            const float sn = fmaf(coef[j], s1[j], xv - s2[j]);
            s2[j] = s1[j];
            s1[j] = sn;
        }
    }
    __syncthreads();   // done reading u/v; lds is re-aliased below

    // per-thread band sums
    float pb[5] = {0.0f, 0.0f, 0.0f, 0.0f, 0.0f};
#pragma unroll
    for (int j = 0; j < 7; ++j) {
        const int f = 1 + g + 8 * j;
        if (f > 50) continue;            // wave-uniform guard
        const float p = fmaf(s1[j], s1[j],
                        fmaf(s2[j], s2[j], -coef[j] * s1[j] * s2[j]));
        if (f <= 4)             pb[0] += p;
        if (f >= 4 && f <= 8)   pb[1] += p;
        if (f >= 8 && f <= 13)  pb[2] += p;
        if (f >= 13 && f <= 30) pb[3] += p;
        if (f >= 30)            pb[4] += p;
    }

    // cross-wave reduction via re-aliased LDS (each (g,k,c) written once)
    float (*bpart)[5][64] = (float (*)[5][64])lds;
#pragma unroll
    for (int k = 0; k < 5; ++k) bpart[g][k][c] = pb[k];
    __syncthreads();

    const float wband[5] = {1.0f / 4.0f, 1.0f / 5.0f, 1.0f / 6.0f,
                            1.0f / 18.0f, 1.0f / 21.0f};
    for (int idx = tid; idx < 320; idx += 512) {
        const int k  = idx >> 6;
        const int cc = idx & 63;
        float s = 0.0f;
#pragma unroll
        for (int gg = 0; gg < 8; ++gg) s += bpart[gg][k][cc];
        feat[(size_t)blk * 320 + idx] = s * wband[k];
    }
}

// ---------------------------------------------------------------------------
// Fused MLP + interp — MEASUREMENT BUILD. Identical structure to round 9,
// but the whole body repeats REPS=3 times (same work, same output values
// written 3x; deterministic). Purpose: push this dispatch's duration above
// the ~155us fill kernels so it lands in the rocprof top-5 with counters.
// kf = (dur_us - k1)/3; k1 = 100.2 - kf_round9 via the round-9 equation.
// ---------------------------------------------------------------------------
__device__ __forceinline__ int i0_of(int t) {
    float pos = ((float)t + 0.5f) * (31.0f / 4096.0f) - 0.5f;
    pos = fminf(fmaxf(pos, 0.0f), 30.0f);
    return (int)pos;
}

__device__ __forceinline__ int span_start(int i) {
    if (i <= 0) return 0;
    if (i >= 31) return TT;
    int t = (int)(((float)i + 0.5f) * (4096.0f / 31.0f) - 0.5f) - 4;
    if (t < 0) t = 0;
    // first t with i0_of(t) >= i (monotone; guess is ~4 below the crossing)
    while (t < TT && i0_of(t) < i) ++t;
    return t;
}

#define REPS 3

__global__ __launch_bounds__(256) void k_fused_probe(const float* __restrict__ feat,
                                                     const float* __restrict__ W1,
                                                     const float* __restrict__ b1,
                                                     const float* __restrict__ W2,
                                                     const float* __restrict__ b2,
                                                     float* __restrict__ out) {
    __shared__ float fs[3][320];
    __shared__ float hs[3][256];
    __shared__ float ABs[3][512];

    const int tid  = threadIdx.x;
    const int blk  = blockIdx.x;         // 0..511
    const int b    = blk >> 4;           // batch
    const int grp  = blk & 15;           // span-pair group
    const int i0s  = grp * 2;            // first span of this block
    const int nSp  = (grp == 15) ? 1 : 2;
    const int r0   = i0s;                // first MLP row

    for (int rep = 0; rep < REPS; ++rep) {
        // stage the (up to) 3 feat rows, row index clamped to 30
#pragma unroll
        for (int r = 0; r < 3; ++r) {
            const int rr = min(r0 + r, NW - 1);
            const float* fr = feat + ((size_t)b * NW + rr) * 320;
            for (int k = tid; k < 320; k += 256) fs[r][k] = fr[k];
        }
        __syncthreads();

        // MLP phase 1: hidden (256), thread owns column tid, 3 rows
        {
            const float bias = b1[tid];
            float a0 = bias, a1 = bias, a2 = bias;
            for (int k = 0; k < 320; ++k) {
                const float w = W1[(size_t)k * 256 + tid];
                a0 = fmaf(fs[0][k], w, a0);
                a1 = fmaf(fs[1][k], w, a1);
                a2 = fmaf(fs[2][k], w, a2);
            }
            hs[0][tid] = fmaxf(a0, 0.0f);
            hs[1][tid] = fmaxf(a1, 0.0f);
            hs[2][tid] = fmaxf(a2, 0.0f);
        }
        __syncthreads();

        // MLP phase 2: output (512), thread owns cols tid, tid+256, 3 rows
        {
            const float bias0 = b2[tid];
            const float bias1 = b2[tid + 256];
            float o00 = bias0, o10 = bias0, o20 = bias0;
            float o01 = bias1, o11 = bias1, o21 = bias1;
            for (int k = 0; k < 256; ++k) {
                const float w0 = W2[(size_t)k * 512 + tid];
                const float w1 = W2[(size_t)k * 512 + tid + 256];
                const float h0 = hs[0][k];
                const float h1 = hs[1][k];
                const float h2 = hs[2][k];
                o00 = fmaf(h0, w0, o00);
                o01 = fmaf(h0, w1, o01);
                o10 = fmaf(h1, w0, o10);
                o11 = fmaf(h1, w1, o11);
                o20 = fmaf(h2, w0, o20);
                o21 = fmaf(h2, w1, o21);
            }
            ABs[0][tid] = o00; ABs[0][tid + 256] = o01;
            ABs[1][tid] = o10; ABs[1][tid + 256] = o11;
            ABs[2][tid] = o20; ABs[2][tid + 256] = o21;
        }
        __syncthreads();

        // store stream: per span, res(t) = A + w(t)*(B-A); pure stores
        const int d4   = tid & 127;          // f32x4 slot within the 512-row
        const int half = tid >> 7;           // 0/1: even/odd t

        for (int s = 0; s < nSp; ++s) {
            const int i     = i0s + s;
            const int r1idx = min(i + 1, NW - 1) - r0;
            const f32x4 va  = ((const f32x4*)ABs[s])[d4];
            const f32x4 vd  = ((const f32x4*)ABs[r1idx])[d4] - va;

            const int tS = span_start(i);
            const int tE = span_start(i + 1);
            for (int t = tS + half; t < tE; t += 2) {
                float pos = ((float)t + 0.5f) * (31.0f / 4096.0f) - 0.5f;
                pos = fminf(fmaxf(pos, 0.0f), 30.0f);
                const float w = pos - (float)i;
                const f32x4 res = va + w * vd;
                f32x4* o = (f32x4*)(out + ((size_t)b * TT + t) * DD);
                o[d4] = res;
            }
        }
        __syncthreads();   // waves may still read ABs; protect fs overwrite
    }
}

// ---------------------------------------------------------------------------
extern "C" void kernel_launch(void* const* d_in, const int* in_sizes, int n_in,
                              void* d_out, int out_size, void* d_ws, size_t ws_size,
                              hipStream_t stream) {
    const float* x  = (const float*)d_in[0];
    const float* W1 = (const float*)d_in[1];
    const float* b1 = (const float*)d_in[2];
    const float* W2 = (const float*)d_in[3];
    const float* b2 = (const float*)d_in[4];
    float* out = (float*)d_out;

    float* feat = (float*)d_ws;                  // NROWS*320 floats = 1.27 MB

    k_bandpower<<<NROWS, 512, 0, stream>>>(x, feat);
    k_fused_probe<<<BB * 16, 256, 0, stream>>>(feat, W1, b1, W2, b2, out);
}

// Round 12
// 106.646 us; speedup vs baseline: 1.9721x; 1.9721x over previous
//
#include <hip/hip_runtime.h>
#include <hip/hip_bf16.h>
#include <math.h>

// Problem constants
#define BB 32
#define TT 4096
#define CC 64
#define DD 512
#define NW 31          // number of windows
#define WIN 256
#define HOP 128
#define NROWS (BB * NW)   // 992

typedef float f32x4 __attribute__((ext_vector_type(4)));

// ---------------------------------------------------------------------------
// Kernel 1: band power via folded Goertzel. (unchanged; measured 9.4 us)
// ---------------------------------------------------------------------------
__global__ __launch_bounds__(512) void k_bandpower(const float* __restrict__ x,
                                                   float* __restrict__ feat) {
    __shared__ float lds[16384];         // 64 KB
    float* u = lds;                      // [128][64]
    float* v = lds + 8192;               // [128][64]

    const int tid = threadIdx.x;
    const int c   = tid & 63;
    const int g   = tid >> 6;            // wave id 0..7
    const int blk = blockIdx.x;          // 0..991
    const int b   = blk / NW;
    const int n   = blk % NW;

    // staged fold: read both halves once, write u,v (coalesced f32x4)
    const size_t winBase = ((size_t)b * TT + (size_t)n * HOP) * CC;
    const f32x4* h0 = (const f32x4*)(x + winBase);              // t = 0..127
    const f32x4* h1 = (const f32x4*)(x + winBase + 128 * CC);   // t = 128..255
    f32x4* u4 = (f32x4*)u;
    f32x4* v4 = (f32x4*)v;
    for (int i = tid; i < 2048; i += 512) {
        const f32x4 a  = h0[i];
        const f32x4 bb = h1[i];
        u4[i] = a + bb;
        v4[i] = a - bb;
    }
    __syncthreads();

    // 7 Goertzel chains per thread, 128 steps, on u (even f) or v (odd f)
    float coef[7], s1[7], s2[7];
#pragma unroll
    for (int j = 0; j < 7; ++j) {
        const int f = 1 + g + 8 * j;
        coef[j] = 2.0f * cospif((float)f * (1.0f / 128.0f)); // 2cos(2pi f/256)
        s1[j] = 0.0f;
        s2[j] = 0.0f;
    }
    // parity(f) = parity(1+g): g odd -> f even -> u; g even -> f odd -> v
    const float* src = ((g & 1) ? u : v) + c;

#pragma unroll 4
    for (int tt = 0; tt < 128; ++tt) {
        const float xv = src[tt * 64];
#pragma unroll
        for (int j = 0; j < 7; ++j) {
            const float sn = fmaf(coef[j], s1[j], xv - s2[j]);
            s2[j] = s1[j];
            s1[j] = sn;
        }
    }
    __syncthreads();   // done reading u/v; lds is re-aliased below

    // per-thread band sums
    float pb[5] = {0.0f, 0.0f, 0.0f, 0.0f, 0.0f};
#pragma unroll
    for (int j = 0; j < 7; ++j) {
        const int f = 1 + g + 8 * j;
        if (f > 50) continue;            // wave-uniform guard
        const float p = fmaf(s1[j], s1[j],
                        fmaf(s2[j], s2[j], -coef[j] * s1[j] * s2[j]));
        if (f <= 4)             pb[0] += p;
        if (f >= 4 && f <= 8)   pb[1] += p;
        if (f >= 8 && f <= 13)  pb[2] += p;
        if (f >= 13 && f <= 30) pb[3] += p;
        if (f >= 30)            pb[4] += p;
    }

    // cross-wave reduction via re-aliased LDS (each (g,k,c) written once)
    float (*bpart)[5][64] = (float (*)[5][64])lds;
#pragma unroll
    for (int k = 0; k < 5; ++k) bpart[g][k][c] = pb[k];
    __syncthreads();

    const float wband[5] = {1.0f / 4.0f, 1.0f / 5.0f, 1.0f / 6.0f,
                            1.0f / 18.0f, 1.0f / 21.0f};
    for (int idx = tid; idx < 320; idx += 512) {
        const int k  = idx >> 6;
        const int cc = idx & 63;
        float s = 0.0f;
#pragma unroll
        for (int gg = 0; gg < 8; ++gg) s += bpart[gg][k][cc];
        feat[(size_t)blk * 320 + idx] = s * wband[k];
    }
}

// ---------------------------------------------------------------------------
// Fused MLP + interp, v4: 1024 threads/block (16 waves), 512 blocks
// -> 32 waves/CU (max occupancy). MLP parallelized across more waves
// (identical per-accumulator FMA order -> bitwise-identical results);
// store phase runs with 4x more waves per CU than v2/v3.
// Block grp<15 owns spans {2g,2g+1}, MLP rows {2g,2g+1,2g+2}; grp15: span 30.
// ---------------------------------------------------------------------------
__device__ __forceinline__ int i0_of(int t) {
    float pos = ((float)t + 0.5f) * (31.0f / 4096.0f) - 0.5f;
    pos = fminf(fmaxf(pos, 0.0f), 30.0f);
    return (int)pos;
}

__device__ __forceinline__ int span_start(int i) {
    if (i <= 0) return 0;
    if (i >= 31) return TT;
    int t = (int)(((float)i + 0.5f) * (4096.0f / 31.0f) - 0.5f) - 4;
    if (t < 0) t = 0;
    // first t with i0_of(t) >= i (monotone; guess is ~4 below the crossing)
    while (t < TT && i0_of(t) < i) ++t;
    return t;
}

__global__ __launch_bounds__(1024) void k_mlp_interp4(const float* __restrict__ feat,
                                                      const float* __restrict__ W1,
                                                      const float* __restrict__ b1,
                                                      const float* __restrict__ W2,
                                                      const float* __restrict__ b2,
                                                      float* __restrict__ out) {
    __shared__ float fs[3][320];
    __shared__ float hs[3][256];
    __shared__ float ABs[3][512];

    const int tid  = threadIdx.x;
    const int blk  = blockIdx.x;         // 0..511
    const int b    = blk >> 4;           // batch
    const int grp  = blk & 15;           // span-pair group
    const int i0s  = grp * 2;            // first span of this block
    const int nSp  = (grp == 15) ? 1 : 2;
    const int r0   = i0s;                // first MLP row

    // stage the (up to) 3 feat rows, row index clamped to 30
#pragma unroll
    for (int r = 0; r < 3; ++r) {
        const int rr = min(r0 + r, NW - 1);
        const float* fr = feat + ((size_t)b * NW + rr) * 320;
        for (int k = tid; k < 320; k += 1024) fs[r][k] = fr[k];
    }
    __syncthreads();

    // MLP phase 1: hidden (256 cols x 3 rows = 768 dots), one per thread.
    // row = tid>>8 (0..3, row 3 idle), col = tid&255. Same k-order FMA chain
    // as v2 -> bitwise-identical hs.
    {
        const int row = tid >> 8;
        const int col = tid & 255;
        if (row < 3) {
            float a = b1[col];
            for (int k = 0; k < 320; ++k)
                a = fmaf(fs[row][k], W1[(size_t)k * 256 + col], a);
            hs[row][col] = fmaxf(a, 0.0f);
        }
    }
    __syncthreads();

    // MLP phase 2: output (512 cols x 3 rows). rsel = tid>>9 (0/1):
    // rsel0 -> rows 0,1 col, rsel1 -> row 2 (plus idle half). col2 = tid&511.
    {
        const int col2 = tid & 511;
        const int rsel = tid >> 9;
        const float bias = b2[col2];
        if (rsel == 0) {
            float o0 = bias, o1 = bias;
            for (int k = 0; k < 256; ++k) {
                const float w = W2[(size_t)k * 512 + col2];
                o0 = fmaf(hs[0][k], w, o0);
                o1 = fmaf(hs[1][k], w, o1);
            }
            ABs[0][col2] = o0;
            ABs[1][col2] = o1;
        } else {
            float o2 = bias;
            for (int k = 0; k < 256; ++k) {
                const float w = W2[(size_t)k * 512 + col2];
                o2 = fmaf(hs[2][k], w, o2);
            }
            ABs[2][col2] = o2;
        }
    }
    __syncthreads();

    // store stream: per span, res(t) = A + w(t)*(B-A); pure contiguous
    // stores from all 16 waves (8 t-slots x 128 lanes per iteration).
    const int d4   = tid & 127;          // f32x4 slot within the 512-row
    const int slot = tid >> 7;           // 0..7: t-slot

    for (int s = 0; s < nSp; ++s) {
        const int i     = i0s + s;
        const int r1idx = min(i + 1, NW - 1) - r0;   // s+1, or 0 for span 30
        const f32x4 va  = ((const f32x4*)ABs[s])[d4];
        const f32x4 vd  = ((const f32x4*)ABs[r1idx])[d4] - va;
        const float fi  = (float)i;

        const int tS = span_start(i);
        const int tE = span_start(i + 1);
        for (int t = tS + slot; t < tE; t += 8) {
            float pos = ((float)t + 0.5f) * (31.0f / 4096.0f) - 0.5f;
            pos = fminf(fmaxf(pos, 0.0f), 30.0f);
            const float w = pos - fi;
            const f32x4 res = va + w * vd;
            f32x4* o = (f32x4*)(out + ((size_t)b * TT + t) * DD);
            o[d4] = res;
        }
        __syncthreads();   // ABs reused as-is next span; cheap, keeps waves together
    }
}

// ---------------------------------------------------------------------------
extern "C" void kernel_launch(void* const* d_in, const int* in_sizes, int n_in,
                              void* d_out, int out_size, void* d_ws, size_t ws_size,
                              hipStream_t stream) {
    const float* x  = (const float*)d_in[0];
    const float* W1 = (const float*)d_in[1];
    const float* b1 = (const float*)d_in[2];
    const float* W2 = (const float*)d_in[3];
    const float* b2 = (const float*)d_in[4];
    float* out = (float*)d_out;

    float* feat = (float*)d_ws;                  // NROWS*320 floats = 1.27 MB

    k_bandpower<<<NROWS, 512, 0, stream>>>(x, feat);
    k_mlp_interp4<<<BB * 16, 1024, 0, stream>>>(feat, W1, b1, W2, b2, out);
}

// Round 13
// 102.843 us; speedup vs baseline: 2.0450x; 1.0370x over previous
//
#include <hip/hip_runtime.h>
#include <hip/hip_bf16.h>
#include <math.h>

// Problem constants
#define BB 32
#define TT 4096
#define CC 64
#define DD 512
#define NW 31          // number of windows
#define WIN 256
#define HOP 128
#define NROWS (BB * NW)   // 992

typedef float f32x4 __attribute__((ext_vector_type(4)));

// Weight sizes in f32x4 units
#define W1_V4 20480       // 320*256/4
#define W2_V4 32768       // 256*512/4
#define WTOT_V4 (W1_V4 + W2_V4)          // 53248
#define WSLICE_V4 (WTOT_V4 / 32)         // 1664

// ---------------------------------------------------------------------------
// Kernel 1: band power via folded Goertzel (measured 9.4 us), plus a
// weight-prefetch tail: the last 256 blocks stream a 1/32 slice of W1+W2
// each (slice = (p>>3)&31 so that under the bid%8 XCD round-robin every
// (XCD, slice) pair is covered) -> warms L3/L2 for the fused kernel's MLP,
// whose cold-weight load latency (~900cyc/miss, L2+L3 flushed by the
// harness's poison fills every replay) measured ~20-25us.
// ---------------------------------------------------------------------------
__global__ __launch_bounds__(512) void k_bandpower(const float* __restrict__ x,
                                                   const float* __restrict__ W1,
                                                   const float* __restrict__ W2,
                                                   float* __restrict__ feat) {
    __shared__ float lds[16384];         // 64 KB
    float* u = lds;                      // [128][64]
    float* v = lds + 8192;               // [128][64]

    const int tid = threadIdx.x;
    const int c   = tid & 63;
    const int g   = tid >> 6;            // wave id 0..7
    const int blk = blockIdx.x;          // 0..991
    const int b   = blk / NW;
    const int n   = blk % NW;

    // staged fold: read both halves once, write u,v (coalesced f32x4)
    const size_t winBase = ((size_t)b * TT + (size_t)n * HOP) * CC;
    const f32x4* h0 = (const f32x4*)(x + winBase);              // t = 0..127
    const f32x4* h1 = (const f32x4*)(x + winBase + 128 * CC);   // t = 128..255
    f32x4* u4 = (f32x4*)u;
    f32x4* v4 = (f32x4*)v;
    for (int i = tid; i < 2048; i += 512) {
        const f32x4 a  = h0[i];
        const f32x4 bb = h1[i];
        u4[i] = a + bb;
        v4[i] = a - bb;
    }
    __syncthreads();

    // 7 Goertzel chains per thread, 128 steps, on u (even f) or v (odd f)
    float coef[7], s1[7], s2[7];
#pragma unroll
    for (int j = 0; j < 7; ++j) {
        const int f = 1 + g + 8 * j;
        coef[j] = 2.0f * cospif((float)f * (1.0f / 128.0f)); // 2cos(2pi f/256)
        s1[j] = 0.0f;
        s2[j] = 0.0f;
    }
    // parity(f) = parity(1+g): g odd -> f even -> u; g even -> f odd -> v
    const float* src = ((g & 1) ? u : v) + c;

#pragma unroll 4
    for (int tt = 0; tt < 128; ++tt) {
        const float xv = src[tt * 64];
#pragma unroll
        for (int j = 0; j < 7; ++j) {
            const float sn = fmaf(coef[j], s1[j], xv - s2[j]);
            s2[j] = s1[j];
            s1[j] = sn;
        }
    }
    __syncthreads();   // done reading u/v; lds is re-aliased below

    // per-thread band sums
    float pb[5] = {0.0f, 0.0f, 0.0f, 0.0f, 0.0f};
#pragma unroll
    for (int j = 0; j < 7; ++j) {
        const int f = 1 + g + 8 * j;
        if (f > 50) continue;            // wave-uniform guard
        const float p = fmaf(s1[j], s1[j],
                        fmaf(s2[j], s2[j], -coef[j] * s1[j] * s2[j]));
        if (f <= 4)             pb[0] += p;
        if (f >= 4 && f <= 8)   pb[1] += p;
        if (f >= 8 && f <= 13)  pb[2] += p;
        if (f >= 13 && f <= 30) pb[3] += p;
        if (f >= 30)            pb[4] += p;
    }

    // cross-wave reduction via re-aliased LDS (each (g,k,c) written once)
    float (*bpart)[5][64] = (float (*)[5][64])lds;
#pragma unroll
    for (int k = 0; k < 5; ++k) bpart[g][k][c] = pb[k];
    __syncthreads();

    const float wband[5] = {1.0f / 4.0f, 1.0f / 5.0f, 1.0f / 6.0f,
                            1.0f / 18.0f, 1.0f / 21.0f};
    for (int idx = tid; idx < 320; idx += 512) {
        const int k  = idx >> 6;
        const int cc = idx & 63;
        float s = 0.0f;
#pragma unroll
        for (int gg = 0; gg < 8; ++gg) s += bpart[gg][k][cc];
        feat[(size_t)blk * 320 + idx] = s * wband[k];
    }

    // ---- weight-prefetch tail (last 256 blocks) ----
    if (blk >= NROWS - 256) {
        const int p     = blk - (NROWS - 256);   // 0..255
        const int slice = (p >> 3) & 31;         // 8 XCD-phases x 32 slices
        const f32x4* w1v = (const f32x4*)W1;
        const f32x4* w2v = (const f32x4*)W2;
        float acc = 0.0f;
        for (int q = tid; q < WSLICE_V4; q += 512) {
            const int idx = slice * WSLICE_V4 + q;
            const f32x4 val = (idx < W1_V4) ? w1v[idx] : w2v[idx - W1_V4];
            acc += val.x + val.y + val.z + val.w;
        }
        asm volatile("" :: "v"(acc));    // keep loads live (no DCE)
    }
}

// ---------------------------------------------------------------------------
// Fused MLP + interp (round-7 structure, measured best at 97.8us).
// One block per (b, span i): 992 blocks. Computes the MLP for rows i and
// i+1, then streams its span with a load-free contiguous store loop.
// MLP k-loops unrolled x4 for deeper outstanding-load pipelining.
// ---------------------------------------------------------------------------
__device__ __forceinline__ int i0_of(int t) {
    float pos = ((float)t + 0.5f) * (31.0f / 4096.0f) - 0.5f;
    pos = fminf(fmaxf(pos, 0.0f), 30.0f);
    return (int)pos;
}

__device__ __forceinline__ int span_start(int i) {
    if (i <= 0) return 0;
    if (i >= 31) return TT;
    int t = (int)(((float)i + 0.5f) * (4096.0f / 31.0f) - 0.5f) - 4;
    if (t < 0) t = 0;
    // first t with i0_of(t) >= i (monotone; guess is ~4 below the crossing)
    while (t < TT && i0_of(t) < i) ++t;
    return t;
}

__global__ __launch_bounds__(256) void k_mlp_interp(const float* __restrict__ feat,
                                                    const float* __restrict__ W1,
                                                    const float* __restrict__ b1,
                                                    const float* __restrict__ W2,
                                                    const float* __restrict__ b2,
                                                    float* __restrict__ out) {
    __shared__ float fs[2][320];
    __shared__ float hs[2][256];
    __shared__ float ABs[2][512];

    const int tid = threadIdx.x;
    const int blk = blockIdx.x;          // 0..991
    const int b   = blk / NW;
    const int i   = blk % NW;            // this block's i0 span
    const int r1  = min(i + 1, NW - 1);

    // stage the two feat rows
    const float* f0 = feat + ((size_t)b * NW + i) * 320;
    const float* f1 = feat + ((size_t)b * NW + r1) * 320;
    for (int k = tid; k < 320; k += 256) {
        fs[0][k] = f0[k];
        fs[1][k] = f1[k];
    }
    __syncthreads();

    // MLP phase 1: hidden (256), thread owns column tid, both rows
    {
        float a0 = b1[tid], a1 = a0;
#pragma unroll 4
        for (int k = 0; k < 320; ++k) {
            const float w = W1[(size_t)k * 256 + tid];
            a0 = fmaf(fs[0][k], w, a0);
            a1 = fmaf(fs[1][k], w, a1);
        }
        hs[0][tid] = fmaxf(a0, 0.0f);
        hs[1][tid] = fmaxf(a1, 0.0f);
    }
    __syncthreads();

    // MLP phase 2: output (512), thread owns columns tid and tid+256, both rows
    {
        float o00 = b2[tid], o01 = b2[tid + 256];
        float o10 = o00,     o11 = o01;
#pragma unroll 4
        for (int k = 0; k < 256; ++k) {
            const float w0 = W2[(size_t)k * 512 + tid];
            const float w1 = W2[(size_t)k * 512 + tid + 256];
            const float h0 = hs[0][k];
            const float h1 = hs[1][k];
            o00 = fmaf(h0, w0, o00);
            o01 = fmaf(h0, w1, o01);
            o10 = fmaf(h1, w0, o10);
            o11 = fmaf(h1, w1, o11);
        }
        ABs[0][tid] = o00; ABs[0][tid + 256] = o01;
        ABs[1][tid] = o10; ABs[1][tid + 256] = o11;
    }
    __syncthreads();

    // interp stream: res(t) = A + w(t) * (B - A), pure stores
    const int d4   = tid & 127;          // f32x4 slot within the 512-row
    const int half = tid >> 7;           // 0/1: even/odd t of each pair
    const f32x4 va = ((const f32x4*)ABs[0])[d4];
    const f32x4 vd = ((const f32x4*)ABs[1])[d4] - va;

    const int tS = span_start(i);
    const int tE = span_start(i + 1);

    for (int t = tS + half; t < tE; t += 2) {
        float pos = ((float)t + 0.5f) * (31.0f / 4096.0f) - 0.5f;
        pos = fminf(fmaxf(pos, 0.0f), 30.0f);
        const float w = pos - (float)i;
        const f32x4 res = va + w * vd;
        f32x4* o = (f32x4*)(out + ((size_t)b * TT + t) * DD);
        o[d4] = res;
    }
}

// ---------------------------------------------------------------------------
extern "C" void kernel_launch(void* const* d_in, const int* in_sizes, int n_in,
                              void* d_out, int out_size, void* d_ws, size_t ws_size,
                              hipStream_t stream) {
    const float* x  = (const float*)d_in[0];
    const float* W1 = (const float*)d_in[1];
    const float* b1 = (const float*)d_in[2];
    const float* W2 = (const float*)d_in[3];
    const float* b2 = (const float*)d_in[4];
    float* out = (float*)d_out;

    float* feat = (float*)d_ws;                  // NROWS*320 floats = 1.27 MB

    k_bandpower<<<NROWS, 512, 0, stream>>>(x, W1, W2, feat);
    k_mlp_interp<<<NROWS, 256, 0, stream>>>(feat, W1, b1, W2, b2, out);
}